// Round 1
// 18440.388 us; speedup vs baseline: 1.2534x; 1.2534x over previous
//
#include <hip/hip_runtime.h>
#include <math.h>

// Problem constants
#define BQ 256   // batch
#define NN 1024  // nodes
#define EE 256   // embed
#define HH 8     // heads
#define TS 64    // decode steps
#define SCALE 0.17677669529663687f  // 1/sqrt(32)
#define CLIPC 10.0f

// ---------------------------------------------------------------------------
// Init: zero visited, state init, sum of x over nodes (for masked mean).
// ---------------------------------------------------------------------------
__global__ __launch_bounds__(256) void init_kernel(
    const float* __restrict__ x, const float* __restrict__ cap0,
    float* __restrict__ sum_embed, float* __restrict__ cnt,
    float* __restrict__ capb, int* __restrict__ curb,
    unsigned char* __restrict__ visited)
{
    int b = blockIdx.x, tid = threadIdx.x;
    #pragma unroll
    for (int i = 0; i < 4; i++) visited[b * NN + tid + i * 256] = 0;
    if (tid == 0) { cnt[b] = 1024.0f; capb[b] = cap0[b]; curb[b] = 0; }
    const float* xb = x + (size_t)b * NN * EE + tid;
    float s = 0.f;
    #pragma unroll 8
    for (int n = 0; n < NN; n++) s += xb[(size_t)n * EE];
    sum_embed[b * EE + tid] = s;
}

// ---------------------------------------------------------------------------
// Fused per-step kernel, one block per batch, 512 threads (8 waves).
// Never materializes K/V/KP: streams x twice per step (scores+wsum pass with
// online softmax; pointer-logit pass), everything else is tiny matvecs.
// ---------------------------------------------------------------------------
__global__ __launch_bounds__(512) void step_kernel(
    const float* __restrict__ x, const float* __restrict__ demand,
    const float* __restrict__ Wc, const float* __restrict__ bc,
    const float* __restrict__ Wqkv, const float* __restrict__ bqkv,
    const float* __restrict__ Wo, const float* __restrict__ bo,
    const float* __restrict__ Wpq, const float* __restrict__ bpq,
    const float* __restrict__ Wpk, const float* __restrict__ bpk,
    float* __restrict__ sum_embed, float* __restrict__ cntb,
    float* __restrict__ capb, int* __restrict__ curb,
    unsigned char* __restrict__ visited,
    float* __restrict__ probs_out, float* __restrict__ route_out, int t)
{
    // 8 waves x 16KB x-tiles (16 nodes x 256 floats, XOR-swizzled granules)
    __shared__ __align__(16) float xs[32768];     // 128 KB
    __shared__ __align__(16) float g8[2048];      // g[8][256] -> wsumF -> htil
    __shared__ __align__(16) float ptl[8][16][8]; // per-wave p-tilde
    __shared__ unsigned char masksh[NN];
    __shared__ float cvec[513];
    __shared__ float vevec[EE];
    __shared__ __align__(16) float qvec[EE];
    __shared__ float ctxv[EE];
    __shared__ float cov[EE];
    __shared__ __align__(16) float qpv[EE];
    __shared__ float uvec[NN];
    __shared__ float skk[512];
    __shared__ float mw_s[64], sw_s[64];
    __shared__ float MM[HH], SS[HH];
    __shared__ float red[8];
    __shared__ int   redi[8];
    __shared__ float s_mx, s_sum, s_ubias;
    __shared__ int   s_node;

    int b = blockIdx.x, tid = threadIdx.x;
    int w = tid >> 6, l = tid & 63;
    float capv = capb[b];
    int cur = curb[b];
    const float* xb = x + (size_t)b * NN * EE;

    // ---- phase A: mask -----------------------------------------------------
    {
        uchar2 vis = *(const uchar2*)(visited + b * NN + tid * 2);
        float2 dem = *(const float2*)(demand + b * NN + tid * 2);
        bool m0 = (vis.x != 0) || (dem.x > capv);
        bool m1 = (vis.y != 0) || (dem.y > capv);
        if (tid == 0 && cur == 0) m0 = true;
        masksh[tid * 2]     = m0 ? 1 : 0;
        masksh[tid * 2 + 1] = m1 ? 1 : 0;
        int allm = __syncthreads_and((m0 && m1) ? 1 : 0);
        if (allm && tid == 0) masksh[0] = 0;
    }
    // ---- phase A: cvec = [mean, sel, cap] ----------------------------------
    if (tid < EE) {
        cvec[tid]      = sum_embed[b * EE + tid] / cntb[b];
        cvec[EE + tid] = xb[(size_t)cur * EE + tid];
    }
    if (tid == 0) cvec[512] = capv;
    __syncthreads();
    // ---- phase A: ve = cvec @ Wc + bc (split-k over 2 halves) --------------
    {
        int c = tid & 255, half = tid >> 8;
        int i0 = half * 256, i1 = half ? 513 : 256;
        float acc = 0.f;
        #pragma unroll 8
        for (int i = i0; i < i1; i++) acc = fmaf(cvec[i], Wc[i * EE + c], acc);
        skk[tid] = acc;
        __syncthreads();
        if (tid < EE) vevec[tid] = skk[tid] + skk[256 + tid] + bc[tid];
        __syncthreads();
    }
    // ---- phase A: q = ve @ Wq + bq -----------------------------------------
    {
        int c = tid & 255, half = tid >> 8;
        float acc = 0.f;
        #pragma unroll 8
        for (int i = half * 128; i < half * 128 + 128; i++)
            acc = fmaf(vevec[i], Wqkv[(size_t)i * 768 + c], acc);
        skk[tid] = acc;
        __syncthreads();
        if (tid < EE) qvec[tid] = skk[tid] + skk[256 + tid] + bqkv[tid];
        __syncthreads();
    }
    // ---- phase A: g[h][e] = SCALE * sum_d q[h*32+d]*Wk[e][h*32+d] ----------
    {
        int e = tid & 255, half = tid >> 8;   // half -> heads 4h..4h+3
        const float* wr = Wqkv + (size_t)e * 768 + 256 + half * 128;
        const float* qh = qvec + half * 128;
        float a4[4] = {0.f, 0.f, 0.f, 0.f};
        #pragma unroll
        for (int k = 0; k < 32; k++) {
            float4 wv = *(const float4*)(wr + k * 4);
            float4 q4 = *(const float4*)(qh + k * 4);
            a4[k >> 3] = fmaf(wv.x, q4.x, fmaf(wv.y, q4.y,
                         fmaf(wv.z, q4.z, fmaf(wv.w, q4.w, a4[k >> 3]))));
        }
        #pragma unroll
        for (int hh2 = 0; hh2 < 4; hh2++)
            g8[(half * 4 + hh2) * EE + e] = SCALE * a4[hh2];
    }
    __syncthreads();

    // ---- phase B: stream x once; scores (8 heads) + online-softmax wsum ----
    float* xw = xs + w * 4096;    // this wave's 16-node tile
    int qtr = l >> 4, r = l & 15;
    float wsv[8][4] = {};
    float mrun[8], srun[8];
    #pragma unroll
    for (int h = 0; h < 8; h++) { mrun[h] = -INFINITY; srun[h] = 0.f; }

    for (int tt = 0; tt < 8; tt++) {
        int n0 = (w + tt * 8) * 16;
        // stage tile: row i, granule l stored at slot l^(i&7) (swizzle)
        float4 stg[16];
        #pragma unroll
        for (int i = 0; i < 16; i++)
            stg[i] = *(const float4*)(xb + (size_t)(n0 + i) * EE + l * 4);
        #pragma unroll
        for (int i = 0; i < 16; i++)
            *(float4*)(xw + i * 256 + ((l ^ (i & 7)) << 2)) = stg[i];
        // scores: lane = (node r, e-quarter qtr); read each xs granule once,
        // accumulate all 8 heads; quarter-rotation spreads g8 bank quads
        float sacc[8] = {0.f, 0.f, 0.f, 0.f, 0.f, 0.f, 0.f, 0.f};
        #pragma unroll
        for (int gi = 0; gi < 16; gi++) {
            int c = qtr * 16 + ((gi + 2 * qtr) & 15);
            float4 xv = *(const float4*)(xw + r * 256 + ((c ^ (r & 7)) << 2));
            #pragma unroll
            for (int h = 0; h < 8; h++) {
                float4 gv = *(const float4*)(g8 + h * EE + (c << 2));
                sacc[h] = fmaf(xv.x, gv.x, fmaf(xv.y, gv.y,
                          fmaf(xv.z, gv.z, fmaf(xv.w, gv.w, sacc[h]))));
            }
        }
        int n = n0 + r;
        bool msk = masksh[n] != 0;
        float ptv[8], fac[8];
        #pragma unroll
        for (int h = 0; h < 8; h++) {
            float v = sacc[h];
            v += __shfl_xor(v, 16);
            v += __shfl_xor(v, 32);
            v = msk ? -INFINITY : v;
            float tm = v;
            tm = fmaxf(tm, __shfl_xor(tm, 1));
            tm = fmaxf(tm, __shfl_xor(tm, 2));
            tm = fmaxf(tm, __shfl_xor(tm, 4));
            tm = fmaxf(tm, __shfl_xor(tm, 8));
            float mo = mrun[h];
            float mn = fmaxf(mo, tm);
            float f  = (mo == -INFINITY) ? 0.f : expf(mo - mn);
            float pt = msk ? 0.f : expf(v - mn);
            float tsum = pt;
            tsum += __shfl_xor(tsum, 1);
            tsum += __shfl_xor(tsum, 2);
            tsum += __shfl_xor(tsum, 4);
            tsum += __shfl_xor(tsum, 8);
            srun[h] = fmaf(srun[h], f, tsum);
            mrun[h] = mn;
            fac[h] = f; ptv[h] = pt;
        }
        #pragma unroll
        for (int h = 0; h < 8; h++) {
            wsv[h][0] *= fac[h]; wsv[h][1] *= fac[h];
            wsv[h][2] *= fac[h]; wsv[h][3] *= fac[h];
        }
        if (qtr == 0) {
            *(float4*)&ptl[w][r][0] = make_float4(ptv[0], ptv[1], ptv[2], ptv[3]);
            *(float4*)&ptl[w][r][4] = make_float4(ptv[4], ptv[5], ptv[6], ptv[7]);
        }
        // wsum: lane = e-granule l; whole swizzled row per node, conflict-free
        #pragma unroll
        for (int nd = 0; nd < 16; nd++) {
            float4 xv = *(const float4*)(xw + nd * 256 + ((l ^ (nd & 7)) << 2));
            float4 pa = *(const float4*)&ptl[w][nd][0];
            float4 pb = *(const float4*)&ptl[w][nd][4];
#define WSACC(H, P) \
            wsv[H][0] = fmaf(P, xv.x, wsv[H][0]); \
            wsv[H][1] = fmaf(P, xv.y, wsv[H][1]); \
            wsv[H][2] = fmaf(P, xv.z, wsv[H][2]); \
            wsv[H][3] = fmaf(P, xv.w, wsv[H][3]);
            WSACC(0, pa.x) WSACC(1, pa.y) WSACC(2, pa.z) WSACC(3, pa.w)
            WSACC(4, pb.x) WSACC(5, pb.y) WSACC(6, pb.z) WSACC(7, pb.w)
#undef WSACC
        }
    }
    // ---- merge 8 waves' online stats + wsum partials -----------------------
    if (l == 0) {
        #pragma unroll
        for (int h = 0; h < 8; h++) { mw_s[w * 8 + h] = mrun[h]; sw_s[w * 8 + h] = srun[h]; }
    }
    __syncthreads();
    if (tid < 8) {
        float M = -INFINITY;
        for (int w2 = 0; w2 < 8; w2++) M = fmaxf(M, mw_s[w2 * 8 + tid]);
        float S = 0.f;
        for (int w2 = 0; w2 < 8; w2++) {
            float mm = mw_s[w2 * 8 + tid];
            if (mm > -INFINITY) S += sw_s[w2 * 8 + tid] * expf(mm - M);
        }
        MM[tid] = M; SS[tid] = S;
    }
    __syncthreads();
    #pragma unroll
    for (int h = 0; h < 8; h++) {
        float mm = mrun[h];
        float f = (mm > -INFINITY) ? expf(mm - MM[h]) : 0.f;
        *(float4*)(xs + (w * 8 + h) * 256 + l * 4) =
            make_float4(wsv[h][0] * f, wsv[h][1] * f, wsv[h][2] * f, wsv[h][3] * f);
    }
    __syncthreads();
    #pragma unroll
    for (int k = 0; k < 4; k++) {
        int idx = tid + k * 512;      // idx = h*256 + e
        float s = 0.f;
        #pragma unroll
        for (int w2 = 0; w2 < 8; w2++) s += xs[w2 * 2048 + idx];
        g8[idx] = s;                   // wsumF
    }
    __syncthreads();

    // ---- phase C: ctx = wsumF@Wv/S + bv ------------------------------------
    {
        int c = tid & 255, half = tid >> 8;
        int h2 = c >> 5;
        const float* wv = Wqkv + 512 + c;
        float acc = 0.f;
        #pragma unroll 8
        for (int e = half * 128; e < half * 128 + 128; e++)
            acc = fmaf(g8[h2 * EE + e], wv[(size_t)e * 768], acc);
        skk[tid] = acc;
        __syncthreads();
        if (tid < EE) ctxv[tid] = (skk[tid] + skk[256 + tid]) / SS[tid >> 5] + bqkv[512 + tid];
        __syncthreads();
    }
    // co = ctx @ Wo + bo
    {
        int c = tid & 255, half = tid >> 8;
        float acc = 0.f;
        #pragma unroll 8
        for (int i = half * 128; i < half * 128 + 128; i++)
            acc = fmaf(ctxv[i], Wo[(size_t)i * EE + c], acc);
        skk[tid] = acc;
        __syncthreads();
        if (tid < EE) cov[tid] = skk[tid] + skk[256 + tid] + bo[tid];
        __syncthreads();
    }
    // qp = co @ Wpq + bpq
    {
        int c = tid & 255, half = tid >> 8;
        float acc = 0.f;
        #pragma unroll 8
        for (int i = half * 128; i < half * 128 + 128; i++)
            acc = fmaf(cov[i], Wpq[(size_t)i * EE + c], acc);
        skk[tid] = acc;
        __syncthreads();
        if (tid < EE) qpv[tid] = skk[tid] + skk[256 + tid] + bpq[tid];
        __syncthreads();
    }
    // ubias = qp . bpk
    {
        float v = (tid < EE) ? qpv[tid] * bpk[tid] : 0.f;
        #pragma unroll
        for (int o = 32; o > 0; o >>= 1) v += __shfl_down(v, o);
        if (l == 0) red[w] = v;
        __syncthreads();
        if (tid == 0) {
            float s2 = 0.f;
            for (int i = 0; i < 8; i++) s2 += red[i];
            s_ubias = s2;
        }
    }
    // htil[e] = sum_c Wpk[e][c]*qp[c]  (overwrites g8[0..255])
    {
        __syncthreads();
        int e = tid & 255, half = tid >> 8;
        const float* wr = Wpk + (size_t)e * EE + half * 128;
        const float* qh = qpv + half * 128;
        float acc = 0.f;
        #pragma unroll
        for (int k = 0; k < 32; k++) {
            float4 wv = *(const float4*)(wr + k * 4);
            float4 q4 = *(const float4*)(qh + k * 4);
            acc = fmaf(wv.x, q4.x, fmaf(wv.y, q4.y,
                  fmaf(wv.z, q4.z, fmaf(wv.w, q4.w, acc))));
        }
        skk[tid] = acc;
        __syncthreads();
        if (tid < EE) g8[tid] = skk[tid] + skk[256 + tid];
        __syncthreads();
    }

    // ---- phase D: stream x again; u = 10*tanh(x.htil + ubias) --------------
    float ubias = s_ubias;
    for (int tt = 0; tt < 8; tt++) {
        int n0 = (w + tt * 8) * 16;
        float4 stg[16];
        #pragma unroll
        for (int i = 0; i < 16; i++)
            stg[i] = *(const float4*)(xb + (size_t)(n0 + i) * EE + l * 4);
        #pragma unroll
        for (int i = 0; i < 16; i++)
            *(float4*)(xw + i * 256 + ((l ^ (i & 7)) << 2)) = stg[i];
        float acc = 0.f;
        #pragma unroll
        for (int gi = 0; gi < 16; gi++) {
            int c = qtr * 16 + ((gi + 2 * qtr) & 15);
            float4 xv = *(const float4*)(xw + r * 256 + ((c ^ (r & 7)) << 2));
            float4 hv = *(const float4*)(g8 + (c << 2));
            acc = fmaf(xv.x, hv.x, fmaf(xv.y, hv.y,
                  fmaf(xv.z, hv.z, fmaf(xv.w, hv.w, acc))));
        }
        acc += __shfl_xor(acc, 16);
        acc += __shfl_xor(acc, 32);
        if (qtr == 0) {
            int n = n0 + r;
            uvec[n] = masksh[n] ? -INFINITY : CLIPC * tanhf(acc + ubias);
        }
    }
    __syncthreads();

    // ---- masked softmax over u, probs write, argmax, state update ----------
    float u0 = uvec[tid], u1 = uvec[tid + 512];
    float lmax = fmaxf(u0, u1);
    #pragma unroll
    for (int o = 32; o > 0; o >>= 1) lmax = fmaxf(lmax, __shfl_down(lmax, o));
    if (l == 0) red[w] = lmax;
    __syncthreads();
    if (tid == 0) {
        float m2 = red[0];
        for (int i = 1; i < 8; i++) m2 = fmaxf(m2, red[i]);
        s_mx = m2;
    }
    __syncthreads();
    float mx = s_mx;
    float p0 = (u0 == -INFINITY) ? 0.f : expf(u0 - mx);
    float p1 = (u1 == -INFINITY) ? 0.f : expf(u1 - mx);
    float ls = p0 + p1;
    #pragma unroll
    for (int o = 32; o > 0; o >>= 1) ls += __shfl_down(ls, o);
    if (l == 0) red[w] = ls;
    __syncthreads();
    if (tid == 0) {
        float s2 = 0.f;
        for (int i = 0; i < 8; i++) s2 += red[i];
        s_sum = s2;
    }
    __syncthreads();
    float sm = s_sum;
    p0 = p0 / sm; p1 = p1 / sm;
    size_t pbase = (size_t)t * BQ * NN + (size_t)b * NN;
    probs_out[pbase + tid] = p0;
    probs_out[pbase + tid + 512] = p1;
    float bu; int bn;
    if (p1 > p0) { bu = p1; bn = tid + 512; } else { bu = p0; bn = tid; }
    #pragma unroll
    for (int o = 32; o > 0; o >>= 1) {
        float ou = __shfl_down(bu, o);
        int   on = __shfl_down(bn, o);
        if (ou > bu || (ou == bu && on < bn)) { bu = ou; bn = on; }
    }
    if (l == 0) { red[w] = bu; redi[w] = bn; }
    __syncthreads();
    if (tid == 0) {
        float vv = red[0]; int nd = redi[0];
        for (int i = 1; i < 8; i++)
            if (red[i] > vv || (red[i] == vv && redi[i] < nd)) { vv = red[i]; nd = redi[i]; }
        s_node = nd;
        route_out[t * BQ + b] = (float)nd;
        capb[b] = capv - demand[b * NN + nd];
        curb[b] = nd;
        if (nd != 0) { visited[b * NN + nd] = 1; cntb[b] -= 1.f; }
    }
    __syncthreads();
    int node = s_node;
    if (node != 0 && tid < EE)
        sum_embed[b * EE + tid] -= xb[(size_t)node * EE + tid];
}

// ---------------------------------------------------------------------------
extern "C" void kernel_launch(void* const* d_in, const int* in_sizes, int n_in,
                              void* d_out, int out_size, void* d_ws, size_t ws_size,
                              hipStream_t stream) {
    const float* x      = (const float*)d_in[0];
    const float* demand = (const float*)d_in[1];
    const float* cap0   = (const float*)d_in[2];
    const float* Wc     = (const float*)d_in[3];
    const float* bc     = (const float*)d_in[4];
    const float* Wqkv   = (const float*)d_in[5];
    const float* bqkv   = (const float*)d_in[6];
    const float* Wo     = (const float*)d_in[7];
    const float* bo     = (const float*)d_in[8];
    const float* Wpq    = (const float*)d_in[9];
    const float* bpq    = (const float*)d_in[10];
    const float* Wpk    = (const float*)d_in[11];
    const float* bpk    = (const float*)d_in[12];
    float* out = (float*)d_out;

    float* sum_embed = (float*)d_ws;                 // [B,E]
    float* cnt       = sum_embed + 65536;            // [B]
    float* capbuf    = cnt + 256;                    // [B]
    int*   curbuf    = (int*)(capbuf + 256);         // [B]
    unsigned char* visited = (unsigned char*)(curbuf + 256);  // [B,N]

    float* probs_out = out;                          // [T,B,N]
    float* route_out = out + (size_t)TS * BQ * NN;   // [T,B]

    hipLaunchKernelGGL(init_kernel, dim3(BQ), dim3(256), 0, stream,
                       x, cap0, sum_embed, cnt, capbuf, curbuf, visited);
    for (int t = 0; t < TS; t++) {
        hipLaunchKernelGGL(step_kernel, dim3(BQ), dim3(512), 0, stream,
                           x, demand, Wc, bc, Wqkv, bqkv, Wo, bo, Wpq, bpq,
                           Wpk, bpk, sum_embed, cnt, capbuf, curbuf, visited,
                           probs_out, route_out, t);
    }
}